// Round 1
// baseline (196.866 us; speedup 1.0000x reference)
//
#include <hip/hip_runtime.h>
#include <hip/hip_bf16.h>
#include <stdint.h>

#define LSEQ 2048
#define BATCH 2
#define DMODEL 1024
#define NH 16
#define HD 64

typedef __attribute__((ext_vector_type(8))) short bf16x8;
typedef __attribute__((ext_vector_type(4))) float f32x4;

__device__ __forceinline__ short f2bf(float f) {
  union { float f; uint32_t u; } v; v.f = f;
  uint32_t r = v.u + 0x7fffu + ((v.u >> 16) & 1u);
  return (short)(r >> 16);
}

__device__ __forceinline__ void gll16(const void* g, void* l) {
  __builtin_amdgcn_global_load_lds(
      (const __attribute__((address_space(1))) void*)g,
      (__attribute__((address_space(3))) void*)l, 16, 0, 0);
}

// ---------------- fp32 -> bf16 convert (vectorized) ----------------
__global__ void cvt_bf16(const float* __restrict__ in, short* __restrict__ out, int n) {
  int i = (blockIdx.x * blockDim.x + threadIdx.x) * 4;
  if (i < n) {
    float4 v = *(const float4*)(in + i);
    short4 o;
    o.x = f2bf(v.x); o.y = f2bf(v.y); o.z = f2bf(v.z); o.w = f2bf(v.w);
    *(short4*)(out + i) = o;
  }
}

// ---------------- transpose + convert: out[n][k] = bf16(in[k][n]) ----------------
__global__ void transpose_cvt(const float* __restrict__ in, short* __restrict__ out,
                              int K, int N) {
  __shared__ float tile[32][33];
  int kb = blockIdx.x * 32, nb = blockIdx.y * 32;
  int tx = threadIdx.x & 31, ty = threadIdx.x >> 5;
  #pragma unroll
  for (int i = ty; i < 32; i += 8)
    tile[i][tx] = in[(size_t)(kb + i) * N + nb + tx];
  __syncthreads();
  #pragma unroll
  for (int i = ty; i < 32; i += 8)
    out[(size_t)(nb + i) * K + kb + tx] = f2bf(tile[tx][i]);
}

// ---------------- 128x128 bf16 GEMM, Bt input [N][K], K=1024 ----------------
// EPI=0: qkv epilogue (bias, q*0.125, scatter q/k [B,H,L,64], v transposed [B,H,64,L])
// EPI=1: fp32 out + bias
template <int EPI>
__global__ __launch_bounds__(256, 2) void gemm_bt(
    const short* __restrict__ A, const short* __restrict__ Bt,
    const float* __restrict__ bias, float* __restrict__ outf,
    short* __restrict__ q_out, short* __restrict__ k_out, short* __restrict__ v_out) {
  constexpr int K = 1024, BK = 32;
  __shared__ short Als[128 * BK];
  __shared__ short Bls[128 * BK];
  const int tid = threadIdx.x;
  const int lane = tid & 63;
  const int m0 = blockIdx.x * 128;
  const int n0 = blockIdx.y * 128;
  const int wid = tid >> 6;
  const int wm = (wid >> 1) * 64, wn = (wid & 1) * 64;

  f32x4 acc[4][4] = {};

  for (int kt = 0; kt < K / BK; ++kt) {
    const int k0 = kt * BK;
    __syncthreads();
    #pragma unroll
    for (int inst = 0; inst < 2; ++inst) {
      int c = inst * 256 + tid;
      int row = c >> 2, cc = (c & 3) * 8;
      gll16(A + (size_t)(m0 + row) * K + k0 + cc, Als + c * 8);
      gll16(Bt + (size_t)(n0 + row) * K + k0 + cc, Bls + c * 8);
    }
    __syncthreads();
    bf16x8 af[4], bfv[4];
    #pragma unroll
    for (int m = 0; m < 4; ++m)
      af[m] = *(const bf16x8*)(Als + (wm + m * 16 + (lane & 15)) * BK + (lane >> 4) * 8);
    #pragma unroll
    for (int n = 0; n < 4; ++n)
      bfv[n] = *(const bf16x8*)(Bls + (wn + n * 16 + (lane & 15)) * BK + (lane >> 4) * 8);
    #pragma unroll
    for (int m = 0; m < 4; ++m)
      #pragma unroll
      for (int n = 0; n < 4; ++n)
        acc[m][n] = __builtin_amdgcn_mfma_f32_16x16x32_bf16(af[m], bfv[n], acc[m][n], 0, 0, 0);
  }

  #pragma unroll
  for (int m = 0; m < 4; ++m) {
    #pragma unroll
    for (int n = 0; n < 4; ++n) {
      #pragma unroll
      for (int r = 0; r < 4; ++r) {
        int row = m0 + wm + m * 16 + (lane >> 4) * 4 + r;
        int col = n0 + wn + n * 16 + (lane & 15);
        float val = acc[m][n][r] + bias[col];
        if (EPI == 1) {
          outf[(size_t)row * DMODEL + col] = val;
        } else {
          int b = row >> 11, l = row & 2047;
          int which = col >> 10, rem = col & 1023;
          int hn = rem >> 6, d = rem & 63;
          size_t bh = (size_t)b * NH + hn;
          if (which == 0)       q_out[(bh * LSEQ + l) * HD + d] = f2bf(val * 0.125f);
        else if (which == 1)  k_out[(bh * LSEQ + l) * HD + d] = f2bf(val);
          else                  v_out[(bh * HD + d) * LSEQ + l] = f2bf(val);
        }
      }
    }
  }
}

// ---------------- fused attention: QK^T + rel-bias + mask + online softmax + PV ----------------
__global__ __launch_bounds__(256, 2) void attn_kernel(
    const short* __restrict__ qb, const short* __restrict__ kb,
    const short* __restrict__ vtb, const unsigned char* __restrict__ kpm,
    const float* __restrict__ bias_table, short* __restrict__ ob) {
  __shared__ short Kls[64 * 64];
  __shared__ short Vls[64 * 64];
  __shared__ short Pls[4][16 * 64];
  __shared__ float biasc[257];
  __shared__ float maskls[64];

  const int tid = threadIdx.x, lane = tid & 63, wid = tid >> 6;
  const int q0 = blockIdx.x * 64, h = blockIdx.y, b = blockIdx.z;
  const size_t bh = (size_t)b * NH + h;
  const short* qbase = qb + bh * LSEQ * HD;
  const short* kbase = kb + bh * LSEQ * HD;
  const short* vbase = vtb + bh * HD * LSEQ;

  for (int i = tid; i < 257; i += 256) biasc[i] = bias_table[i * NH + h];

  const int qrow_frag = q0 + wid * 16 + (lane & 15);
  bf16x8 qf[2];
  #pragma unroll
  for (int ks = 0; ks < 2; ++ks)
    qf[ks] = *(const bf16x8*)(qbase + (size_t)qrow_frag * HD + ks * 32 + (lane >> 4) * 8);

  float m_run[4], l_run[4];
  f32x4 o[4];
  #pragma unroll
  for (int r = 0; r < 4; ++r) { m_run[r] = -1e30f; l_run[r] = 0.f; }
  #pragma unroll
  for (int nt = 0; nt < 4; ++nt) o[nt] = (f32x4){0.f, 0.f, 0.f, 0.f};

  for (int t = 0; t < LSEQ / 64; ++t) {
    const int kv0 = t * 64;
    __syncthreads();
    // stage K [64 keys][64 d] and V^T [64 d][64 keys]; source pre-swizzled, reads swizzled
    #pragma unroll
    for (int inst = 0; inst < 2; ++inst) {
      int c = inst * 256 + tid;
      int row = c >> 3, cc = c & 7;
      int scc = cc ^ (row & 7);
      gll16(kbase + (size_t)(kv0 + row) * HD + scc * 8, Kls + c * 8);
      gll16(vbase + (size_t)row * LSEQ + kv0 + scc * 8, Vls + c * 8);
    }
    if (tid < 64) maskls[tid] = kpm[(size_t)b * LSEQ + kv0 + tid] ? -1e30f : 0.f;
    __syncthreads();

    // S = Q K^T  (q pre-scaled by 0.125)
    f32x4 s[4];
    #pragma unroll
    for (int nt = 0; nt < 4; ++nt) {
      f32x4 a = {};
      #pragma unroll
      for (int ks = 0; ks < 2; ++ks) {
        int krow = nt * 16 + (lane & 15);
        int kbyte = (ks * 32 + (lane >> 4) * 8) * 2;
        const bf16x8 kf =
            *(const bf16x8*)((const char*)Kls + krow * 128 + (kbyte ^ ((krow & 7) << 4)));
        a = __builtin_amdgcn_mfma_f32_16x16x32_bf16(qf[ks], kf, a, 0, 0, 0);
      }
      s[nt] = a;
    }

    // rel-bias + key padding mask
    #pragma unroll
    for (int nt = 0; nt < 4; ++nt) {
      int kcol = kv0 + nt * 16 + (lane & 15);
      float mk = maskls[nt * 16 + (lane & 15)];
      #pragma unroll
      for (int r = 0; r < 4; ++r) {
        int qrow = q0 + wid * 16 + (lane >> 4) * 4 + r;
        int rel = kcol - qrow;
        rel = rel < -128 ? -128 : (rel > 128 ? 128 : rel);
        s[nt][r] += biasc[rel + 128] + mk;
      }
    }

    // online softmax (rows live in 16-lane groups)
    #pragma unroll
    for (int r = 0; r < 4; ++r) {
      float rm = fmaxf(fmaxf(s[0][r], s[1][r]), fmaxf(s[2][r], s[3][r]));
      #pragma unroll
      for (int off = 1; off < 16; off <<= 1) rm = fmaxf(rm, __shfl_xor(rm, off, 16));
      float mn = fmaxf(m_run[r], rm);
      float sc = __expf(m_run[r] - mn);
      m_run[r] = mn;
      l_run[r] *= sc;
      #pragma unroll
      for (int nt = 0; nt < 4; ++nt) o[nt][r] *= sc;
      float ps = 0.f;
      #pragma unroll
      for (int nt = 0; nt < 4; ++nt) {
        float p = __expf(s[nt][r] - mn);
        s[nt][r] = p;
        ps += p;
      }
      #pragma unroll
      for (int off = 1; off < 16; off <<= 1) ps += __shfl_xor(ps, off, 16);
      l_run[r] += ps;
    }

    // P -> LDS (wave-private, swizzled)
    short* pw = &Pls[wid][0];
    #pragma unroll
    for (int nt = 0; nt < 4; ++nt)
      #pragma unroll
      for (int r = 0; r < 4; ++r) {
        int prow = (lane >> 4) * 4 + r;
        int pbyte = (nt * 16 + (lane & 15)) * 2;
        *(short*)((char*)pw + prow * 128 + (pbyte ^ ((prow & 7) << 4))) = f2bf(s[nt][r]);
      }

    // O += P V
    #pragma unroll
    for (int ks = 0; ks < 2; ++ks) {
      int prow = lane & 15;
      int pbyte = (ks * 32 + (lane >> 4) * 8) * 2;
      const bf16x8 pf =
          *(const bf16x8*)((const char*)pw + prow * 128 + (pbyte ^ ((prow & 7) << 4)));
      #pragma unroll
      for (int nt = 0; nt < 4; ++nt) {
        int vrow = nt * 16 + (lane & 15);
        const bf16x8 vf =
            *(const bf16x8*)((const char*)Vls + vrow * 128 + (pbyte ^ ((vrow & 7) << 4)));
        o[nt] = __builtin_amdgcn_mfma_f32_16x16x32_bf16(pf, vf, o[nt], 0, 0, 0);
      }
    }
  }

  #pragma unroll
  for (int r = 0; r < 4; ++r) {
    float inv = 1.f / l_run[r];
    int qrow = q0 + wid * 16 + (lane >> 4) * 4 + r;
    size_t obase = ((size_t)b * LSEQ + qrow) * DMODEL + (size_t)h * HD;
    #pragma unroll
    for (int nt = 0; nt < 4; ++nt)
      ob[obase + nt * 16 + (lane & 15)] = f2bf(o[nt][r] * inv);
  }
}

extern "C" void kernel_launch(void* const* d_in, const int* in_sizes, int n_in,
                              void* d_out, int out_size, void* d_ws, size_t ws_size,
                              hipStream_t stream) {
  (void)in_sizes; (void)n_in; (void)out_size; (void)ws_size;
  const float* x = (const float*)d_in[0];
  const unsigned char* kpm = (const unsigned char*)d_in[1];
  const float* Wqkv = (const float*)d_in[2];
  const float* bqkv = (const float*)d_in[3];
  const float* Wout = (const float*)d_in[4];
  const float* bout = (const float*)d_in[5];
  const float* btab = (const float*)d_in[6];
  float* out = (float*)d_out;

  short* ws = (short*)d_ws;
  short* xbf   = ws;                   // 4,194,304 (also reused as obuf)
  short* wqkvT = xbf + 4194304;        // 3,145,728
  short* woutT = wqkvT + 3145728;      // 1,048,576
  short* qbuf  = woutT + 1048576;      // 4,194,304
  short* kbuf  = qbuf + 4194304;       // 4,194,304
  short* vtbuf = kbuf + 4194304;       // 4,194,304
  short* obuf  = vtbuf + 4194304;      // 4,194,304   (total ~41.9M shorts = 40 MB)

  cvt_bf16<<<dim3(4096), dim3(256), 0, stream>>>(x, xbf, 4194304);
  transpose_cvt<<<dim3(32, 96), dim3(256), 0, stream>>>(Wqkv, wqkvT, 1024, 3072);
  transpose_cvt<<<dim3(32, 32), dim3(256), 0, stream>>>(Wout, woutT, 1024, 1024);

  gemm_bt<0><<<dim3(32, 24), dim3(256), 0, stream>>>(xbf, wqkvT, bqkv, nullptr,
                                                     qbuf, kbuf, vtbuf);
  attn_kernel<<<dim3(32, 16, 2), dim3(256), 0, stream>>>(qbuf, kbuf, vtbuf, kpm, btab, obuf);
  gemm_bt<1><<<dim3(32, 8), dim3(256), 0, stream>>>(obuf, woutT, bout, out,
                                                    nullptr, nullptr, nullptr);
}